// Round 7
// baseline (2036.907 us; speedup 1.0000x reference)
//
#include <hip/hip_runtime.h>
#include <hip/hip_bf16.h>

// RNN: S=128, B=64, E=512, H=1024, V=10000, L=2.  M = S*B = 8192.
// prep -> GEMM X0 -> ONE persistent kernel:
//   blocks 0..127   : layer-0 recurrence (Hh0[t] -> Hh0[t+1])
//   blocks 128..383 : layer-1 recurrence (Hh0[s+1]+Hh1[s] -> Hh1[s+1],
//                     concat weights [Wx1|Wh1], K=2048)
//   blocks 384..1023: logits workers, work-queue over 64x79 tiles, gated
//                     per-timestep-pair on layer-1 mirror flags.
// Handoff protocol v3 (derived from R1..R6 evidence):
//   producer: publish stores -> s_waitcnt vmcnt(0) (all waves) -> barrier ->
//     tid0: fetch_add on PRIVATE line (round-trip delay = the empirically
//     sufficient protection for L2->IC writeback), force-use the returned
//     value, THEN plain-store round number to a separate read-only MIRROR
//     line.  No serialized multi-WG RMW chain.
//   consumer: lane-parallel poll of the 32/64 mirror lines (one IC trip per
//     iteration, __all), then barrier.  Relaxed agent-scope loads for data.

typedef unsigned short u16;
typedef unsigned int   u32;
typedef unsigned long long u64;
typedef __bf16 bf16x8 __attribute__((ext_vector_type(8)));
typedef float  f32x4  __attribute__((ext_vector_type(4)));

__device__ __forceinline__ u16 f2b(float f) {
  __hip_bfloat16 h = __float2bfloat16(f);
  return __builtin_bit_cast(u16, h);
}
__device__ __forceinline__ float b2f(u16 u) {
  return __bfloat162float(__builtin_bit_cast(__hip_bfloat16, u));
}

__device__ __forceinline__ void gload16(const void* g, void* lds) {
  __builtin_amdgcn_global_load_lds(
      (const __attribute__((address_space(1))) u32*)g,
      (__attribute__((address_space(3))) u32*)lds, 16, 0, 0);
}

__device__ __forceinline__ u64 aload64(const u64* p) {
  return __hip_atomic_load(p, __ATOMIC_RELAXED, __HIP_MEMORY_SCOPE_AGENT);
}
__device__ __forceinline__ void astore64(u64* p, u64 v) {
  __hip_atomic_store(p, v, __ATOMIC_RELAXED, __HIP_MEMORY_SCOPE_AGENT);
}
__device__ __forceinline__ int aloadi(const int* p) {
  return __hip_atomic_load(p, __ATOMIC_RELAXED, __HIP_MEMORY_SCOPE_AGENT);
}
__device__ __forceinline__ void astorei(int* p, int v) {
  __hip_atomic_store(p, v, __ATOMIC_RELAXED, __HIP_MEMORY_SCOPE_AGENT);
}

// signal: private RMW round-trip (delay), then mirror store.
__device__ __forceinline__ void signal_round(int* rmw, int* mirror, int val) {
  int old = __hip_atomic_fetch_add(rmw, 1, __ATOMIC_RELAXED,
                                   __HIP_MEMORY_SCOPE_AGENT);
  asm volatile("" ::"v"(old));  // force the RMW round-trip to complete
  astorei(mirror, val);
}

// ---------------------------------------------------------------- prep
__device__ __forceinline__ void cvt4(const float* __restrict__ s,
                                     u16* __restrict__ d, int n4,
                                     int gid, int stride) {
  for (int i = gid; i < n4; i += stride) {
    float4 f = ((const float4*)s)[i];
    ushort4 u;
    u.x = f2b(f.x); u.y = f2b(f.y); u.z = f2b(f.z); u.w = f2b(f.w);
    ((ushort4*)d)[i] = u;
  }
}

__global__ __launch_bounds__(256) void prep_kernel(
    const int* __restrict__ inputs, const float* __restrict__ hidden,
    const float* __restrict__ emb,
    const float* __restrict__ Wx0, const float* __restrict__ Wh0,
    const float* __restrict__ Wx1, const float* __restrict__ Wh1,
    const float* __restrict__ Wout,
    u16* Wx0b, u16* Wh0b, u16* Wcat1, u16* Woutb,
    u16* A0b, u16* Hh0, u16* Hh1, int* flags) {
  int gid = blockIdx.x * 256 + threadIdx.x;
  int stride = gridDim.x * 256;
  if (gid < 12352) flags[gid] = 0;
  cvt4(Wx0, Wx0b, 1024 * 512 / 4, gid, stride);
  cvt4(Wh0, Wh0b, 1024 * 1024 / 4, gid, stride);
  cvt4(Wout, Woutb, 10000 * 1024 / 4, gid, stride);
  cvt4(hidden, Hh0, 65536 / 4, gid, stride);            // slot 0 = h0 init
  cvt4(hidden + 65536, Hh1, 65536 / 4, gid, stride);    // slot 0 = h1 init
  // Wcat1[c][0..1023]=Wx1[c][:], [1024..2047]=Wh1[c][:]
  for (int i = gid; i < 1024 * 512; i += stride) {
    int row = i >> 9, j = i & 511;
    float4 f = (j < 256) ? ((const float4*)Wx1)[row * 256 + j]
                         : ((const float4*)Wh1)[row * 256 + (j - 256)];
    ushort4 u;
    u.x = f2b(f.x); u.y = f2b(f.y); u.z = f2b(f.z); u.w = f2b(f.w);
    ((ushort4*)Wcat1)[i] = u;
  }
  // embedding gather -> bf16 A0 (8192 x 512)
  for (int i = gid; i < 8192 * 128; i += stride) {
    int m = i >> 7, e4 = i & 127;
    int r = inputs[m];
    float4 f = ((const float4*)(emb + (size_t)r * 512))[e4];
    ushort4 u;
    u.x = f2b(f.x); u.y = f2b(f.y); u.z = f2b(f.z); u.w = f2b(f.w);
    ((ushort4*)A0b)[i] = u;
  }
}

// ---------------------------------------------------------------- GEMM (X0)
__global__ __launch_bounds__(256) void gemm_bt(
    const u16* __restrict__ A, const u16* __restrict__ Bm,
    const float* __restrict__ bias, u16* __restrict__ Cout,
    int M, int N, int K) {
  const int tid = threadIdx.x;
  const int l = tid & 63;
  const int wv = tid >> 6;
  const int MT = M >> 7;
  const int bm = (int)blockIdx.x % MT;
  const int bn = (int)blockIdx.x / MT;
  const int m0 = bm * 128, n0 = bn * 128;

  __shared__ u16 As[128 * 32];
  __shared__ u16 Bs[128 * 32];

  const int fa0 = wv * 1024 + l * 16;
  const int fa1 = (4 + wv) * 1024 + l * 16;
  const int rowA0 = fa0 >> 6, kO0 = (fa0 & 63) >> 1;
  const int rowA1 = fa1 >> 6, kO1 = (fa1 & 63) >> 1;
  const u16* gA0 = A + (size_t)(m0 + rowA0) * K + kO0;
  const u16* gA1 = A + (size_t)(m0 + rowA1) * K + kO1;
  const u16* gB0 = Bm + (size_t)(n0 + rowA0) * K + kO0;
  const u16* gB1 = Bm + (size_t)(n0 + rowA1) * K + kO1;
  u16* lA0 = As + wv * 512;
  u16* lA1 = As + (4 + wv) * 512;
  u16* lB0 = Bs + wv * 512;
  u16* lB1 = Bs + (4 + wv) * 512;

  const int wm = wv >> 1, wn = wv & 1;
  const u16* pA = As + (wm * 64 + (l & 15)) * 32 + (l >> 4) * 8;
  const u16* pB = Bs + (wn * 64 + (l & 15)) * 32 + (l >> 4) * 8;

  f32x4 acc[4][4] = {};

  for (int k0 = 0; k0 < K; k0 += 32) {
    __syncthreads();
    gload16(gA0 + k0, lA0);
    gload16(gA1 + k0, lA1);
    gload16(gB0 + k0, lB0);
    gload16(gB1 + k0, lB1);
    asm volatile("s_waitcnt vmcnt(0)" ::: "memory");
    __syncthreads();
    bf16x8 a[4], b[4];
#pragma unroll
    for (int i = 0; i < 4; ++i) a[i] = *(const bf16x8*)(pA + i * 512);
#pragma unroll
    for (int j = 0; j < 4; ++j) b[j] = *(const bf16x8*)(pB + j * 512);
#pragma unroll
    for (int i = 0; i < 4; ++i)
#pragma unroll
      for (int j = 0; j < 4; ++j)
        acc[i][j] = __builtin_amdgcn_mfma_f32_16x16x32_bf16(a[i], b[j],
                                                            acc[i][j], 0, 0, 0);
  }

#pragma unroll
  for (int j = 0; j < 4; ++j) {
    int cn = n0 + wn * 64 + j * 16 + (l & 15);
    float bv = bias[cn];
#pragma unroll
    for (int i = 0; i < 4; ++i) {
      int rmb = m0 + wm * 64 + i * 16 + ((l >> 4) << 2);
#pragma unroll
      for (int r = 0; r < 4; ++r)
        Cout[(size_t)(rmb + r) * N + cn] = f2b(acc[i][j][r] + bv);
    }
  }
}

// ------------------------------------------------ persistent fused kernel
// flags layout (ints, 64B lines):
//   flagL0  = flags +     0  : 128 private RMW lines, (bg*32+cc)<<4
//   flagL0m = flags +  2048  : 128 mirror lines (read-only for pollers)
//   flagL1  = flags +  4096  : 256 private RMW lines, (bg*64+cc)<<4
//   flagL1m = flags +  8192  : 256 mirror lines
//   workq   = flags + 12288
__global__ __launch_bounds__(256, 4) void rnn_fused(
    const u16* __restrict__ X0, const u16* __restrict__ Wh0b,
    const u16* __restrict__ Wcat1, const float* __restrict__ bh1,
    u16* __restrict__ Hh0, u16* __restrict__ Hh1,
    const u16* __restrict__ Woutb, const float* __restrict__ bout,
    float* __restrict__ outL,
    float* __restrict__ hfin0, float* __restrict__ hfin1,
    int* __restrict__ flags) {
  __shared__ __align__(16) char smem[16512];
  const int tid = threadIdx.x;
  const int l = tid & 63;
  const int wv = tid >> 6;
  int* flagL0  = flags;
  int* flagL0m = flags + 2048;
  int* flagL1  = flags + 4096;
  int* flagL1m = flags + 8192;

  if (blockIdx.x < 128) {
    // ---------------- layer 0
    float (*red)[16][16] = (float(*)[16][16])smem;
    u16* ht = (u16*)(smem + 3072);
    const int wg = (int)blockIdx.x;
    const int bg = wg & 3, cc = wg >> 2;
    const int cw = wv & 1, kw = wv >> 1;
    const int col = cc * 32 + cw * 16 + (l & 15);
    const int arow = bg * 16 + (l & 15);
    const int kbase = kw * 512 + ((l >> 4) * 8);
    bf16x8 b[16];
    {
      const u16* wp = Wh0b + (size_t)col * 1024 + kbase;
#pragma unroll
      for (int kt = 0; kt < 16; ++kt) b[kt] = *(const bf16x8*)(wp + kt * 32);
    }
    int* myrmw = flagL0 + ((bg * 32 + cc) << 4);
    int* mymir = flagL0m + ((bg * 32 + cc) << 4);
    const int* pollp = flagL0m + ((bg * 32 + (l & 31)) << 4);

    for (int t = 0; t < 128; ++t) {
      // X prefetch (independent of h) — in flight under the poll
      float xv[4];
      if (kw == 0) {
#pragma unroll
        for (int r = 0; r < 4; ++r) {
          int bat = bg * 16 + (l >> 4) * 4 + r;
          xv[r] = b2f(X0[(size_t)(t * 64 + bat) * 1024 + col]);
        }
      }
      if (t > 0 && tid < 64) {  // wave 0: lane-parallel mirror poll
        for (;;) {
          int f = aloadi(pollp);
          if (__all(f >= t)) break;
          __builtin_amdgcn_s_sleep(1);
        }
      }
      __syncthreads();
      const u64* ap =
          (const u64*)(Hh0 + ((size_t)t * 64 + arow) * 1024 + kbase);
      f32x4 acc = {0.f, 0.f, 0.f, 0.f};
#pragma unroll
      for (int kt = 0; kt < 16; ++kt) {
        union { u64 q[2]; bf16x8 v; } ua;
        ua.q[0] = aload64(ap + kt * 8);
        ua.q[1] = aload64(ap + kt * 8 + 1);
        acc = __builtin_amdgcn_mfma_f32_16x16x32_bf16(ua.v, b[kt], acc, 0, 0, 0);
      }
      if (kw == 1) {
#pragma unroll
        for (int r = 0; r < 4; ++r) red[cw][(l >> 4) * 4 + r][l & 15] = acc[r];
      }
      __syncthreads();
      if (kw == 0) {
#pragma unroll
        for (int r = 0; r < 4; ++r) {
          int br = (l >> 4) * 4 + r;
          float v = acc[r] + red[cw][br][l & 15] + xv[r];
          v = tanhf(v);
          ht[br * 32 + cw * 16 + (l & 15)] = f2b(v);
          if (t == 127) hfin0[(bg * 16 + br) * 1024 + col] = v;
        }
      }
      __syncthreads();
      if (tid < 128) {  // publish 16 rows x 64B into Hh0[t+1]
        int row = tid >> 3, seg = tid & 7;
        u64 v = ((const u64*)ht)[tid];
        u64* dp = (u64*)(Hh0 + ((size_t)(t + 1) * 64 + bg * 16 + row) * 1024 +
                         cc * 32) + seg;
        astore64(dp, v);
      }
      asm volatile("s_waitcnt vmcnt(0)" ::: "memory");  // per-wave drain
      __syncthreads();
      if (tid == 0) signal_round(myrmw, mymir, t + 1);
    }
  } else if (blockIdx.x < 384) {
    // ---------------- layer 1 (K = 2048 concat: h0[s] then h1[s-1])
    float (*red)[16][16] = (float(*)[16][16])smem;
    u16* ht = (u16*)(smem + 3072);
    const int wg = (int)blockIdx.x - 128;
    const int bg = wg & 3, cc = wg >> 2;       // cc 0..63
    const int kw = wv;                          // 0..3
    const int col = cc * 16 + (l & 15);
    const int arow = bg * 16 + (l & 15);
    const int kk = kw * 512 + ((l >> 4) * 8);   // 0..2047
    bf16x8 b[16];
    {
      const u16* wp = Wcat1 + (size_t)col * 2048 + kk;
#pragma unroll
      for (int kt = 0; kt < 16; ++kt) b[kt] = *(const bf16x8*)(wp + kt * 32);
    }
    const float bias = bh1[col];
    int* myrmw = flagL1 + ((bg * 64 + cc) << 4);
    int* mymir = flagL1m + ((bg * 64 + cc) << 4);
    const int* poll0 = flagL0m + ((bg * 32 + (l & 31)) << 4);
    const int* poll1 = flagL1m + ((bg * 64 + l) << 4);

    for (int s = 0; s < 128; ++s) {
      if (tid < 64) {  // wave 0: need flagL0m >= s+1 and flagL1m >= s
        for (;;) {
          int f0 = aloadi(poll0);
          int f1 = aloadi(poll1);
          if (__all(f0 >= s + 1 && f1 >= s)) break;
          __builtin_amdgcn_s_sleep(2);
        }
      }
      __syncthreads();
      const u16* abase =
          (kw < 2)
              ? Hh0 + ((size_t)(s + 1) * 64 + arow) * 1024 + kw * 512 +
                    ((l >> 4) * 8)
              : Hh1 + ((size_t)s * 64 + arow) * 1024 + (kw - 2) * 512 +
                    ((l >> 4) * 8);
      const u64* ap = (const u64*)abase;
      f32x4 acc = {0.f, 0.f, 0.f, 0.f};
#pragma unroll
      for (int kt = 0; kt < 16; ++kt) {
        union { u64 q[2]; bf16x8 v; } ua;
        ua.q[0] = aload64(ap + kt * 8);
        ua.q[1] = aload64(ap + kt * 8 + 1);
        acc = __builtin_amdgcn_mfma_f32_16x16x32_bf16(ua.v, b[kt], acc, 0, 0, 0);
      }
      if (kw != 0) {
#pragma unroll
        for (int r = 0; r < 4; ++r)
          red[kw - 1][(l >> 4) * 4 + r][l & 15] = acc[r];
      }
      __syncthreads();
      if (kw == 0) {
#pragma unroll
        for (int r = 0; r < 4; ++r) {
          int br = (l >> 4) * 4 + r;
          int c = l & 15;
          float v = acc[r] + red[0][br][c] + red[1][br][c] + red[2][br][c] +
                    bias;
          v = tanhf(v);
          ht[br * 16 + c] = f2b(v);
          if (s == 127) hfin1[(bg * 16 + br) * 1024 + col] = v;
        }
      }
      __syncthreads();
      if (tid < 64) {  // publish 16 rows x 32B into Hh1[s+1]
        int row = tid >> 2, seg = tid & 3;
        u64 v = ((const u64*)ht)[tid];
        u64* dp = (u64*)(Hh1 + ((size_t)(s + 1) * 64 + bg * 16 + row) * 1024 +
                         cc * 16) + seg;
        astore64(dp, v);
      }
      asm volatile("s_waitcnt vmcnt(0)" ::: "memory");
      __syncthreads();
      if (tid == 0) signal_round(myrmw, mymir, s + 1);
    }
  } else {
    // ---------------- logits workers: C[8192,10000] = Hh1[1..] @ Wout^T + b
    u16* As = (u16*)smem;
    u16* Bs = (u16*)(smem + 8192);
    int* shid = (int*)(smem + 16384);
    int* workq = flags + 12288;

    const int fa0 = wv * 1024 + l * 16;
    const int fa1 = (4 + wv) * 1024 + l * 16;
    const int rowA0 = fa0 >> 6, kO0 = (fa0 & 63) >> 1;
    const int rowA1 = fa1 >> 6, kO1 = (fa1 & 63) >> 1;
    const u16* Abase = Hh1 + 65536;  // skip slot 0
    u16* lB0 = Bs + wv * 512;
    u16* lB1 = Bs + (4 + wv) * 512;
    u64* dA0 = (u64*)((char*)As + wv * 1024 + l * 16);
    u64* dA1 = (u64*)((char*)As + (4 + wv) * 1024 + l * 16);
    const int wm = wv >> 1, wn = wv & 1;
    const u16* pA = As + (wm * 64 + (l & 15)) * 32 + (l >> 4) * 8;
    const u16* pB = Bs + (wn * 64 + (l & 15)) * 32 + (l >> 4) * 8;
    const int* pf0 = flagL1m + ((0 * 64 + l) << 4);
    const int* pf1 = flagL1m + ((1 * 64 + l) << 4);
    const int* pf2 = flagL1m + ((2 * 64 + l) << 4);
    const int* pf3 = flagL1m + ((3 * 64 + l) << 4);

    for (;;) {
      if (tid == 0)
        *shid = __hip_atomic_fetch_add(workq, 1, __ATOMIC_RELAXED,
                                       __HIP_MEMORY_SCOPE_AGENT);
      __syncthreads();
      const int id = *shid;
      __syncthreads();
      if (id >= 64 * 79) break;
      const int u = id / 79, nn = id - u * 79;
      const int m0 = u * 128, n0 = nn * 128;

      if (tid < 64) {  // gate: all 4 bgs' mirrors >= 2u+2 (coarse sleep)
        const int tgt = 2 * u + 2;
        for (;;) {
          int ok = (aloadi(pf0) >= tgt) & (aloadi(pf1) >= tgt) &
                   (aloadi(pf2) >= tgt) & (aloadi(pf3) >= tgt);
          if (__all(ok)) break;
          __builtin_amdgcn_s_sleep(16);
        }
      }
      __syncthreads();

      const u16* gA0 = Abase + (size_t)(m0 + rowA0) * 1024 + kO0;
      const u16* gA1 = Abase + (size_t)(m0 + rowA1) * 1024 + kO1;
      int rB0 = n0 + rowA0; if (rB0 >= 10000) rB0 = 9999;
      int rB1 = n0 + rowA1; if (rB1 >= 10000) rB1 = 9999;
      const u16* gB0 = Woutb + (size_t)rB0 * 1024 + kO0;
      const u16* gB1 = Woutb + (size_t)rB1 * 1024 + kO1;

      f32x4 acc[4][4] = {};
      for (int k0 = 0; k0 < 1024; k0 += 32) {
        __syncthreads();
        // A tile via IC-coherent loads (Hh1 written by L1 inside this kernel)
        const u64* pa0 = (const u64*)(gA0 + k0);
        const u64* pa1 = (const u64*)(gA1 + k0);
        u64 a00 = aload64(pa0), a01 = aload64(pa0 + 1);
        u64 a10 = aload64(pa1), a11 = aload64(pa1 + 1);
        gload16(gB0 + k0, lB0);
        gload16(gB1 + k0, lB1);
        dA0[0] = a00; dA0[1] = a01;
        dA1[0] = a10; dA1[1] = a11;
        asm volatile("s_waitcnt vmcnt(0)" ::: "memory");
        __syncthreads();
        bf16x8 a[4], b[4];
#pragma unroll
        for (int i = 0; i < 4; ++i) a[i] = *(const bf16x8*)(pA + i * 512);
#pragma unroll
        for (int j = 0; j < 4; ++j) b[j] = *(const bf16x8*)(pB + j * 512);
#pragma unroll
        for (int i = 0; i < 4; ++i)
#pragma unroll
          for (int j = 0; j < 4; ++j)
            acc[i][j] = __builtin_amdgcn_mfma_f32_16x16x32_bf16(
                a[i], b[j], acc[i][j], 0, 0, 0);
      }
#pragma unroll
      for (int j = 0; j < 4; ++j) {
        int cn = n0 + wn * 64 + j * 16 + (l & 15);
        if (cn >= 10000) continue;
        float bv = bout[cn];
#pragma unroll
        for (int i = 0; i < 4; ++i) {
          int rmb = m0 + wm * 64 + i * 16 + ((l >> 4) << 2);
#pragma unroll
          for (int r = 0; r < 4; ++r)
            outL[(size_t)(rmb + r) * 10000 + cn] = acc[i][j][r] + bv;
        }
      }
    }
  }
}

// ---------------------------------------------------------------- launch
extern "C" void kernel_launch(void* const* d_in, const int* in_sizes, int n_in,
                              void* d_out, int out_size, void* d_ws,
                              size_t ws_size, hipStream_t stream) {
  const int*   inputs = (const int*)d_in[0];
  const float* hidden = (const float*)d_in[1];
  const float* emb    = (const float*)d_in[2];
  const float* Wx0    = (const float*)d_in[3];
  const float* Wh0    = (const float*)d_in[4];
  const float* bh0    = (const float*)d_in[5];
  const float* Wx1    = (const float*)d_in[6];
  const float* Wh1    = (const float*)d_in[7];
  const float* bh1    = (const float*)d_in[8];
  const float* Wout   = (const float*)d_in[9];
  const float* bout   = (const float*)d_in[10];
  float* out = (float*)d_out;

  if (ws_size < (size_t)88 * 1024 * 1024) return;

  char* w = (char*)d_ws;
  u16* Wx0b  = (u16*)w; w += 1048576;     // 1024x512
  u16* Wh0b  = (u16*)w; w += 2097152;     // 1024x1024
  u16* Wcat1 = (u16*)w; w += 4194304;     // 1024x2048
  u16* Woutb = (u16*)w; w += 20480000;    // 10000x1024
  u16* A0b   = (u16*)w; w += 8388608;     // 8192x512
  u16* X0b   = (u16*)w; w += 16777216;    // 8192x1024
  u16* Hh0   = (u16*)w; w += 16908288;    // 129x64x1024
  u16* Hh1   = (u16*)w; w += 16908288;    // 129x64x1024
  int* flags = (int*)w;                   // 12352 ints (flag lines + workq)

  float* hfin0 = out + 81920000;
  float* hfin1 = out + 81920000 + 65536;

  prep_kernel<<<2048, 256, 0, stream>>>(inputs, hidden, emb, Wx0, Wh0, Wx1,
                                        Wh1, Wout, Wx0b, Wh0b, Wcat1, Woutb,
                                        A0b, Hh0, Hh1, flags);
  // X0 = emb_gathered @ Wx0^T + bh0   (8192 x 1024, K=512)
  gemm_bt<<<512, 256, 0, stream>>>(A0b, Wx0b, bh0, X0b, 8192, 1024, 512);
  // persistent: 2-layer recurrence + overlapped logits GEMM
  rnn_fused<<<1024, 256, 0, stream>>>(X0b, Wh0b, Wcat1, bh1, Hh0, Hh1, Woutb,
                                      bout, out, hfin0, hfin1, flags);
}

// Round 8
// 1037.237 us; speedup vs baseline: 1.9638x; 1.9638x over previous
//
#include <hip/hip_runtime.h>
#include <hip/hip_bf16.h>

// RNN: S=128, B=64, E=512, H=1024, V=10000, L=2.  M = S*B = 8192.
// prep -> GEMM X0 -> ONE persistent kernel:
//   blocks 0..127   : layer-0 recurrence (Hh0[t] -> Hh0[t+1])
//   blocks 128..383 : layer-1 recurrence (Hh0[s+1]+Hh1[s] -> Hh1[s+1])
//   blocks 384..1023: logits workers (work-queue, gated per timestep-pair)
// Protocol = R6 exactly (best measured): per-bg serialized counter chain,
// winner (fetch_add ret == target-1) broadcasts to a separate done line,
// tid0-ONLY polling everywhere (R7 showed lane-parallel polling congests
// the IC and inflates every handoff).
// NEW vs R6: h-state reads are staged into LDS with COALESCED agent-scope
// loads (contiguous 512B per wave-issue) + XOR swizzle, replacing per-lane
// 2KB-strided aload64 (64 IC lines per issue, 2x duplicated) — cuts IC
// transactions per round ~8-16x.  L1 stages h0/h1 in two phases through one
// 32KB buffer so LDS stays 36KB -> 4 blocks/CU co-residency.

typedef unsigned short u16;
typedef unsigned int   u32;
typedef unsigned long long u64;
typedef __bf16 bf16x8 __attribute__((ext_vector_type(8)));
typedef float  f32x4  __attribute__((ext_vector_type(4)));

__device__ __forceinline__ u16 f2b(float f) {
  __hip_bfloat16 h = __float2bfloat16(f);
  return __builtin_bit_cast(u16, h);
}
__device__ __forceinline__ float b2f(u16 u) {
  return __bfloat162float(__builtin_bit_cast(__hip_bfloat16, u));
}

__device__ __forceinline__ void gload16(const void* g, void* lds) {
  __builtin_amdgcn_global_load_lds(
      (const __attribute__((address_space(1))) u32*)g,
      (__attribute__((address_space(3))) u32*)lds, 16, 0, 0);
}

__device__ __forceinline__ u64 aload64(const u64* p) {
  return __hip_atomic_load(p, __ATOMIC_RELAXED, __HIP_MEMORY_SCOPE_AGENT);
}
__device__ __forceinline__ void astore64(u64* p, u64 v) {
  __hip_atomic_store(p, v, __ATOMIC_RELAXED, __HIP_MEMORY_SCOPE_AGENT);
}
__device__ __forceinline__ int aloadi(const int* p) {
  return __hip_atomic_load(p, __ATOMIC_RELAXED, __HIP_MEMORY_SCOPE_AGENT);
}
__device__ __forceinline__ void astorei(int* p, int v) {
  __hip_atomic_store(p, v, __ATOMIC_RELAXED, __HIP_MEMORY_SCOPE_AGENT);
}

// Stage 16 rows x 2048B from src (agent-scope, coalesced: consecutive tids
// read consecutive 8B) into LDS with XOR swizzle byte^=((row&7)<<4).
__device__ __forceinline__ void stage16(char* hbuf, const u64* src, int tid) {
#pragma unroll
  for (int half = 0; half < 2; ++half) {
    u64 tmp[8];
#pragma unroll
    for (int i = 0; i < 8; ++i)
      tmp[i] = aload64(src + (half * 8 + i) * 256 + tid);
#pragma unroll
    for (int i = 0; i < 8; ++i) {
      int it = half * 8 + i;
      *(u64*)(hbuf + it * 2048 + ((tid * 8) ^ ((it & 7) << 4))) = tmp[i];
    }
  }
}

// ---------------------------------------------------------------- prep
__device__ __forceinline__ void cvt4(const float* __restrict__ s,
                                     u16* __restrict__ d, int n4,
                                     int gid, int stride) {
  for (int i = gid; i < n4; i += stride) {
    float4 f = ((const float4*)s)[i];
    ushort4 u;
    u.x = f2b(f.x); u.y = f2b(f.y); u.z = f2b(f.z); u.w = f2b(f.w);
    ((ushort4*)d)[i] = u;
  }
}

__global__ __launch_bounds__(256) void prep_kernel(
    const int* __restrict__ inputs, const float* __restrict__ hidden,
    const float* __restrict__ emb,
    const float* __restrict__ Wx0, const float* __restrict__ Wh0,
    const float* __restrict__ Wx1, const float* __restrict__ Wh1,
    const float* __restrict__ Wout,
    u16* Wx0b, u16* Wh0b, u16* Wcat1, u16* Woutb,
    u16* A0b, u16* Hh0, u16* Hh1, int* flags) {
  int gid = blockIdx.x * 256 + threadIdx.x;
  int stride = gridDim.x * 256;
  if (gid < 512) flags[gid] = 0;
  cvt4(Wx0, Wx0b, 1024 * 512 / 4, gid, stride);
  cvt4(Wh0, Wh0b, 1024 * 1024 / 4, gid, stride);
  cvt4(Wout, Woutb, 10000 * 1024 / 4, gid, stride);
  cvt4(hidden, Hh0, 65536 / 4, gid, stride);            // slot 0 = h0 init
  cvt4(hidden + 65536, Hh1, 65536 / 4, gid, stride);    // slot 0 = h1 init
  // Wcat1[c][0..1023]=Wx1[c][:], [1024..2047]=Wh1[c][:]
  for (int i = gid; i < 1024 * 512; i += stride) {
    int row = i >> 9, j = i & 511;
    float4 f = (j < 256) ? ((const float4*)Wx1)[row * 256 + j]
                         : ((const float4*)Wh1)[row * 256 + (j - 256)];
    ushort4 u;
    u.x = f2b(f.x); u.y = f2b(f.y); u.z = f2b(f.z); u.w = f2b(f.w);
    ((ushort4*)Wcat1)[i] = u;
  }
  // embedding gather -> bf16 A0 (8192 x 512)
  for (int i = gid; i < 8192 * 128; i += stride) {
    int m = i >> 7, e4 = i & 127;
    int r = inputs[m];
    float4 f = ((const float4*)(emb + (size_t)r * 512))[e4];
    ushort4 u;
    u.x = f2b(f.x); u.y = f2b(f.y); u.z = f2b(f.z); u.w = f2b(f.w);
    ((ushort4*)A0b)[i] = u;
  }
}

// ---------------------------------------------------------------- GEMM (X0)
__global__ __launch_bounds__(256) void gemm_bt(
    const u16* __restrict__ A, const u16* __restrict__ Bm,
    const float* __restrict__ bias, u16* __restrict__ Cout,
    int M, int N, int K) {
  const int tid = threadIdx.x;
  const int l = tid & 63;
  const int wv = tid >> 6;
  const int MT = M >> 7;
  const int bm = (int)blockIdx.x % MT;
  const int bn = (int)blockIdx.x / MT;
  const int m0 = bm * 128, n0 = bn * 128;

  __shared__ u16 As[128 * 32];
  __shared__ u16 Bs[128 * 32];

  const int fa0 = wv * 1024 + l * 16;
  const int fa1 = (4 + wv) * 1024 + l * 16;
  const int rowA0 = fa0 >> 6, kO0 = (fa0 & 63) >> 1;
  const int rowA1 = fa1 >> 6, kO1 = (fa1 & 63) >> 1;
  const u16* gA0 = A + (size_t)(m0 + rowA0) * K + kO0;
  const u16* gA1 = A + (size_t)(m0 + rowA1) * K + kO1;
  const u16* gB0 = Bm + (size_t)(n0 + rowA0) * K + kO0;
  const u16* gB1 = Bm + (size_t)(n0 + rowA1) * K + kO1;
  u16* lA0 = As + wv * 512;
  u16* lA1 = As + (4 + wv) * 512;
  u16* lB0 = Bs + wv * 512;
  u16* lB1 = Bs + (4 + wv) * 512;

  const int wm = wv >> 1, wn = wv & 1;
  const u16* pA = As + (wm * 64 + (l & 15)) * 32 + (l >> 4) * 8;
  const u16* pB = Bs + (wn * 64 + (l & 15)) * 32 + (l >> 4) * 8;

  f32x4 acc[4][4] = {};

  for (int k0 = 0; k0 < K; k0 += 32) {
    __syncthreads();
    gload16(gA0 + k0, lA0);
    gload16(gA1 + k0, lA1);
    gload16(gB0 + k0, lB0);
    gload16(gB1 + k0, lB1);
    asm volatile("s_waitcnt vmcnt(0)" ::: "memory");
    __syncthreads();
    bf16x8 a[4], b[4];
#pragma unroll
    for (int i = 0; i < 4; ++i) a[i] = *(const bf16x8*)(pA + i * 512);
#pragma unroll
    for (int j = 0; j < 4; ++j) b[j] = *(const bf16x8*)(pB + j * 512);
#pragma unroll
    for (int i = 0; i < 4; ++i)
#pragma unroll
      for (int j = 0; j < 4; ++j)
        acc[i][j] = __builtin_amdgcn_mfma_f32_16x16x32_bf16(a[i], b[j],
                                                            acc[i][j], 0, 0, 0);
  }

#pragma unroll
  for (int j = 0; j < 4; ++j) {
    int cn = n0 + wn * 64 + j * 16 + (l & 15);
    float bv = bias[cn];
#pragma unroll
    for (int i = 0; i < 4; ++i) {
      int rmb = m0 + wm * 64 + i * 16 + ((l >> 4) << 2);
#pragma unroll
      for (int r = 0; r < 4; ++r)
        Cout[(size_t)(rmb + r) * N + cn] = f2b(acc[i][j][r] + bv);
    }
  }
}

// ------------------------------------------------ persistent fused kernel
// flags layout (ints, 64B lines):  cnt0[bg]=+0, done0[bg]=+64,
//   cnt1a[bg]=+128, cnt1b[bg]=+192, done1a[bg]=+256, done1b[bg]=+320,
//   workq=+384   (bg index << 4)
__global__ __launch_bounds__(256, 4) void rnn_fused(
    const u16* __restrict__ X0, const u16* __restrict__ Wh0b,
    const u16* __restrict__ Wcat1, const float* __restrict__ bh1,
    u16* __restrict__ Hh0, u16* __restrict__ Hh1,
    const u16* __restrict__ Woutb, const float* __restrict__ bout,
    float* __restrict__ outL,
    float* __restrict__ hfin0, float* __restrict__ hfin1,
    int* __restrict__ flags) {
  __shared__ __align__(16) char smem[36928];
  const int tid = threadIdx.x;
  const int l = tid & 63;
  const int wv = tid >> 6;

  if (blockIdx.x < 128) {
    // ---------------- layer 0
    char* hbuf = smem;                                    // 32 KB staged h
    float (*red)[16][16] = (float(*)[16][16])(smem + 32768);
    u16* ht = (u16*)(smem + 35840);
    const int wg = (int)blockIdx.x;
    const int bg = wg & 3, cc = wg >> 2;
    const int cw = wv & 1, kw = wv >> 1;
    const int col = cc * 32 + cw * 16 + (l & 15);
    const int row = l & 15;
    const int sw = (row & 7) << 4;
    const int rowoff = row * 2048;
    const int kwbase = kw * 1024 + ((l >> 4) << 4);
    bf16x8 b[16];
    {
      const u16* wp = Wh0b + (size_t)col * 1024 + (kw * 512 + ((l >> 4) * 8));
#pragma unroll
      for (int kt = 0; kt < 16; ++kt) b[kt] = *(const bf16x8*)(wp + kt * 32);
    }
    int* cnt0 = flags + (bg << 4);
    int* done0 = flags + 64 + (bg << 4);

    for (int t = 0; t < 128; ++t) {
      float xv[4];
      if (kw == 0) {
#pragma unroll
        for (int r = 0; r < 4; ++r) {
          int bat = bg * 16 + (l >> 4) * 4 + r;
          xv[r] = b2f(X0[(size_t)(t * 64 + bat) * 1024 + col]);
        }
      }
      // stage h[t] (coalesced, swizzled)
      stage16(hbuf, (const u64*)(Hh0 + ((size_t)t * 64 + bg * 16) * 1024), tid);
      __syncthreads();
      f32x4 acc = {0.f, 0.f, 0.f, 0.f};
#pragma unroll
      for (int kt = 0; kt < 16; ++kt) {
        bf16x8 av =
            *(const bf16x8*)(hbuf + rowoff + ((kwbase + kt * 64) ^ sw));
        acc = __builtin_amdgcn_mfma_f32_16x16x32_bf16(av, b[kt], acc, 0, 0, 0);
      }
      if (kw == 1) {
#pragma unroll
        for (int r = 0; r < 4; ++r) red[cw][(l >> 4) * 4 + r][l & 15] = acc[r];
      }
      __syncthreads();
      if (kw == 0) {
#pragma unroll
        for (int r = 0; r < 4; ++r) {
          int br = (l >> 4) * 4 + r;
          float v = acc[r] + red[cw][br][l & 15] + xv[r];
          v = tanhf(v);
          ht[br * 32 + cw * 16 + (l & 15)] = f2b(v);
          if (t == 127) hfin0[(bg * 16 + br) * 1024 + col] = v;
        }
      }
      __syncthreads();
      if (tid < 128) {  // publish 16 rows x 64B into Hh0[t+1]
        int rw = tid >> 3, seg = tid & 7;
        u64 v = ((const u64*)ht)[tid];
        u64* dp = (u64*)(Hh0 + ((size_t)(t + 1) * 64 + bg * 16 + rw) * 1024 +
                         cc * 32) + seg;
        astore64(dp, v);
      }
      asm volatile("s_waitcnt vmcnt(0)" ::: "memory");
      __syncthreads();  // all waves' publishes drained
      if (tid == 0) {
        int old = __hip_atomic_fetch_add(cnt0, 1, __ATOMIC_RELAXED,
                                         __HIP_MEMORY_SCOPE_AGENT);
        if (old == (t + 1) * 32 - 1) {
          astorei(done0, t + 1);   // winner broadcast
        } else if (t < 127) {
          while (aloadi(done0) < t + 1) __builtin_amdgcn_s_sleep(1);
        }
      }
      __syncthreads();
    }
  } else if (blockIdx.x < 384) {
    // ---------------- layer 1 (K = 2048 concat: h0[s] then h1[s-1])
    char* hbuf = smem;                                    // 32 KB, two-phase
    float (*red)[16][16] = (float(*)[16][16])(smem + 32768);
    u16* ht = (u16*)(smem + 35840);
    const int wg = (int)blockIdx.x - 128;
    const int bg = wg & 3, cc = wg >> 2;       // cc 0..63
    const int kw = wv;                          // 0..3
    const int col = cc * 16 + (l & 15);
    const int row = l & 15;
    const int sw = (row & 7) << 4;
    const int rowoff = row * 2048;
    const int kwb = (kw & 1) * 1024 + ((l >> 4) << 4);  // within 16-row buf
    bf16x8 b[16];
    {
      const u16* wp = Wcat1 + (size_t)col * 2048 + (kw * 512 + ((l >> 4) * 8));
#pragma unroll
      for (int kt = 0; kt < 16; ++kt) b[kt] = *(const bf16x8*)(wp + kt * 32);
    }
    const float bias = bh1[col];
    int* done0 = flags + 64 + (bg << 4);
    int* cnt1 = flags + (cc < 32 ? 128 : 192) + (bg << 4);
    int* done1a = flags + 256 + (bg << 4);
    int* done1b = flags + 320 + (bg << 4);
    int* mydone = (cc < 32) ? done1a : done1b;

    for (int s = 0; s < 128; ++s) {
      if (tid == 0) {
        for (;;) {
          if (aloadi(done0) >= s + 1 && aloadi(done1a) >= s &&
              aloadi(done1b) >= s)
            break;
          __builtin_amdgcn_s_sleep(1);
        }
      }
      __syncthreads();
      // phase A: stage h0[s] (= Hh0 slot s+1), waves kw<2 compute
      stage16(hbuf, (const u64*)(Hh0 + ((size_t)(s + 1) * 64 + bg * 16) * 1024),
              tid);
      __syncthreads();
      f32x4 acc = {0.f, 0.f, 0.f, 0.f};
      if (kw < 2) {
#pragma unroll
        for (int kt = 0; kt < 16; ++kt) {
          bf16x8 av = *(const bf16x8*)(hbuf + rowoff + ((kwb + kt * 64) ^ sw));
          acc =
              __builtin_amdgcn_mfma_f32_16x16x32_bf16(av, b[kt], acc, 0, 0, 0);
        }
      }
      __syncthreads();  // phase-A readers done
      // phase B: stage h1[s-1] (= Hh1 slot s), waves kw>=2 compute
      stage16(hbuf, (const u64*)(Hh1 + ((size_t)s * 64 + bg * 16) * 1024), tid);
      __syncthreads();
      if (kw >= 2) {
#pragma unroll
        for (int kt = 0; kt < 16; ++kt) {
          bf16x8 av = *(const bf16x8*)(hbuf + rowoff + ((kwb + kt * 64) ^ sw));
          acc =
              __builtin_amdgcn_mfma_f32_16x16x32_bf16(av, b[kt], acc, 0, 0, 0);
        }
      }
      if (kw != 0) {
#pragma unroll
        for (int r = 0; r < 4; ++r)
          red[kw - 1][(l >> 4) * 4 + r][l & 15] = acc[r];
      }
      __syncthreads();
      if (kw == 0) {
#pragma unroll
        for (int r = 0; r < 4; ++r) {
          int br = (l >> 4) * 4 + r;
          int c = l & 15;
          float v = acc[r] + red[0][br][c] + red[1][br][c] + red[2][br][c] +
                    bias;
          v = tanhf(v);
          ht[br * 16 + c] = f2b(v);
          if (s == 127) hfin1[(bg * 16 + br) * 1024 + col] = v;
        }
      }
      __syncthreads();
      if (tid < 64) {  // publish 16 rows x 32B into Hh1[s+1]
        int rw = tid >> 2, seg = tid & 3;
        u64 v = ((const u64*)ht)[tid];
        u64* dp = (u64*)(Hh1 + ((size_t)(s + 1) * 64 + bg * 16 + rw) * 1024 +
                         cc * 16) + seg;
        astore64(dp, v);
      }
      asm volatile("s_waitcnt vmcnt(0)" ::: "memory");
      __syncthreads();
      if (tid == 0) {
        int old = __hip_atomic_fetch_add(cnt1, 1, __ATOMIC_RELAXED,
                                         __HIP_MEMORY_SCOPE_AGENT);
        if (old == (s + 1) * 32 - 1) astorei(mydone, s + 1);
      }
    }
  } else {
    // ---------------- logits workers: C[8192,10000] = Hh1[1..] @ Wout^T + b
    u16* As = (u16*)smem;
    u16* Bs = (u16*)(smem + 8192);
    int* shid = (int*)(smem + 16384);
    int* workq = flags + 384;
    int* d1a = flags + 256;
    int* d1b = flags + 320;

    const int fa0 = wv * 1024 + l * 16;
    const int fa1 = (4 + wv) * 1024 + l * 16;
    const int rowA0 = fa0 >> 6, kO0 = (fa0 & 63) >> 1;
    const int rowA1 = fa1 >> 6, kO1 = (fa1 & 63) >> 1;
    const u16* Abase = Hh1 + 65536;  // skip slot 0
    u16* lB0 = Bs + wv * 512;
    u16* lB1 = Bs + (4 + wv) * 512;
    u64* dA0 = (u64*)((char*)As + wv * 1024 + l * 16);
    u64* dA1 = (u64*)((char*)As + (4 + wv) * 1024 + l * 16);
    const int wm = wv >> 1, wn = wv & 1;
    const u16* pA = As + (wm * 64 + (l & 15)) * 32 + (l >> 4) * 8;
    const u16* pB = Bs + (wn * 64 + (l & 15)) * 32 + (l >> 4) * 8;

    for (;;) {
      if (tid == 0)
        *shid = __hip_atomic_fetch_add(workq, 1, __ATOMIC_RELAXED,
                                       __HIP_MEMORY_SCOPE_AGENT);
      __syncthreads();
      const int id = *shid;
      __syncthreads();
      if (id >= 64 * 79) break;
      const int u = id / 79, nn = id - u * 79;
      const int m0 = u * 128, n0 = nn * 128;

      if (tid == 0) {  // gate: need Hh1 slots 2u+1, 2u+2 from all 4 bgs
        const int tgt = 2 * u + 2;
        for (;;) {
          int ok = 1;
#pragma unroll
          for (int g = 0; g < 4; ++g)
            ok &= (aloadi(d1a + g * 16) >= tgt) & (aloadi(d1b + g * 16) >= tgt);
          if (ok) break;
          __builtin_amdgcn_s_sleep(4);
        }
      }
      __syncthreads();

      const u16* gA0 = Abase + (size_t)(m0 + rowA0) * 1024 + kO0;
      const u16* gA1 = Abase + (size_t)(m0 + rowA1) * 1024 + kO1;
      int rB0 = n0 + rowA0; if (rB0 >= 10000) rB0 = 9999;
      int rB1 = n0 + rowA1; if (rB1 >= 10000) rB1 = 9999;
      const u16* gB0 = Woutb + (size_t)rB0 * 1024 + kO0;
      const u16* gB1 = Woutb + (size_t)rB1 * 1024 + kO1;

      f32x4 acc[4][4] = {};
      for (int k0 = 0; k0 < 1024; k0 += 32) {
        __syncthreads();
        const u64* pa0 = (const u64*)(gA0 + k0);
        const u64* pa1 = (const u64*)(gA1 + k0);
        u64 a00 = aload64(pa0), a01 = aload64(pa0 + 1);
        u64 a10 = aload64(pa1), a11 = aload64(pa1 + 1);
        gload16(gB0 + k0, lB0);
        gload16(gB1 + k0, lB1);
        dA0[0] = a00; dA0[1] = a01;
        dA1[0] = a10; dA1[1] = a11;
        asm volatile("s_waitcnt vmcnt(0)" ::: "memory");
        __syncthreads();
        bf16x8 a[4], b[4];
#pragma unroll
        for (int i = 0; i < 4; ++i) a[i] = *(const bf16x8*)(pA + i * 512);
#pragma unroll
        for (int j = 0; j < 4; ++j) b[j] = *(const bf16x8*)(pB + j * 512);
#pragma unroll
        for (int i = 0; i < 4; ++i)
#pragma unroll
          for (int j = 0; j < 4; ++j)
            acc[i][j] = __builtin_amdgcn_mfma_f32_16x16x32_bf16(
                a[i], b[j], acc[i][j], 0, 0, 0);
      }
#pragma unroll
      for (int j = 0; j < 4; ++j) {
        int cn = n0 + wn * 64 + j * 16 + (l & 15);
        if (cn >= 10000) continue;
        float bv = bout[cn];
#pragma unroll
        for (int i = 0; i < 4; ++i) {
          int rmb = m0 + wm * 64 + i * 16 + ((l >> 4) << 2);
#pragma unroll
          for (int r = 0; r < 4; ++r)
            outL[(size_t)(rmb + r) * 10000 + cn] = acc[i][j][r] + bv;
        }
      }
    }
  }
}

// ---------------------------------------------------------------- launch
extern "C" void kernel_launch(void* const* d_in, const int* in_sizes, int n_in,
                              void* d_out, int out_size, void* d_ws,
                              size_t ws_size, hipStream_t stream) {
  const int*   inputs = (const int*)d_in[0];
  const float* hidden = (const float*)d_in[1];
  const float* emb    = (const float*)d_in[2];
  const float* Wx0    = (const float*)d_in[3];
  const float* Wh0    = (const float*)d_in[4];
  const float* bh0    = (const float*)d_in[5];
  const float* Wx1    = (const float*)d_in[6];
  const float* Wh1    = (const float*)d_in[7];
  const float* bh1    = (const float*)d_in[8];
  const float* Wout   = (const float*)d_in[9];
  const float* bout   = (const float*)d_in[10];
  float* out = (float*)d_out;

  if (ws_size < (size_t)88 * 1024 * 1024) return;

  char* w = (char*)d_ws;
  u16* Wx0b  = (u16*)w; w += 1048576;     // 1024x512
  u16* Wh0b  = (u16*)w; w += 2097152;     // 1024x1024
  u16* Wcat1 = (u16*)w; w += 4194304;     // 1024x2048
  u16* Woutb = (u16*)w; w += 20480000;    // 10000x1024
  u16* A0b   = (u16*)w; w += 8388608;     // 8192x512
  u16* X0b   = (u16*)w; w += 16777216;    // 8192x1024
  u16* Hh0   = (u16*)w; w += 16908288;    // 129x64x1024
  u16* Hh1   = (u16*)w; w += 16908288;    // 129x64x1024
  int* flags = (int*)w;                   // 512 ints

  float* hfin0 = out + 81920000;
  float* hfin1 = out + 81920000 + 65536;

  prep_kernel<<<2048, 256, 0, stream>>>(inputs, hidden, emb, Wx0, Wh0, Wx1,
                                        Wh1, Wout, Wx0b, Wh0b, Wcat1, Woutb,
                                        A0b, Hh0, Hh1, flags);
  // X0 = emb_gathered @ Wx0^T + bh0   (8192 x 1024, K=512)
  gemm_bt<<<512, 256, 0, stream>>>(A0b, Wx0b, bh0, X0b, 8192, 1024, 512);
  // persistent: 2-layer recurrence + overlapped logits GEMM
  rnn_fused<<<1024, 256, 0, stream>>>(X0b, Wh0b, Wcat1, bh1, Hh0, Hh1, Woutb,
                                      bout, out, hfin0, hfin1, flags);
}